// Round 11
// baseline (306.549 us; speedup 1.0000x reference)
//
#include <hip/hip_runtime.h>

// PatchTrainer: paint 100 filled circles (last-wins) over a 3x4096x4096 fp32 image.
// Per pixel: out = colors[max covering dot] else patch. Write-streaming.
// Ledger: R4 scan-depth null; R5 occupancy null; R6b plane-sep null; R7 nt -4us;
//         R8 (weak cull) profile datum: latency/issue-bound, bytes ideal;
//         R9 de-indirection null; R10 AoS+endpoint-classification null.
// Kernel share pinned ~55us vs 31us write roofline, invariant to inner-loop cost.
// R11: temporal-structure levers (the only remaining difference vs 6.5TB/s fill):
//   (a) STORE BURST: fully unroll 8 row-iters, keep 8 output float4s in registers
//       (static indexing), then 8 back-to-back nt stores per wave covering 8
//       CONSECUTIVE rows -> many stores in flight per wave, fill-like duty cycle.
//   (b) PREP KERNEL: dot table {xc,yc,r2,col} per (plane,dot) built once in
//       workspace; per-block setup = 100 coalesced dwordx4 L2-hot loads instead
//       of ~400 scattered scalar loads (setup was ~50% of block lifetime).

#define IMG  4096
#define ND   100
#define TW   256   // tile width  (64 lanes x float4 = one full row per wave)
#define TH   32    // tile height (4 waves x 8 consecutive rows each)
#define NBX  (IMG / TW)          // 16
#define NBY  (IMG / TH)          // 128

typedef float vfloat4 __attribute__((ext_vector_type(4)));

__global__ __launch_bounds__(128) void prep_dots(
    const float* __restrict__ centers,  // [100][2]
    const float* __restrict__ radii,    // [100]
    const float* __restrict__ colors,   // [100][3]
    float4* __restrict__ table)         // [3][100] {xc, yc, r2, col_z}
{
    const int i = threadIdx.x;
    const int z = blockIdx.x;
    if (i < ND) {
        // Bit-exact replication of the reference's fp32 math:
        float xc = floorf(centers[2 * i]     * 4096.0f);
        float yc = floorf(centers[2 * i + 1] * 4096.0f);
        float r  = floorf(radii[i] * (4096.0f / 5.0f));
        table[z * ND + i] = make_float4(xc, yc, r * r, colors[3 * i + z]);
    }
}

__global__ __launch_bounds__(256) void patch_dots_kernel(
    const float*  __restrict__ patch,   // [3][4096][4096]
    const float4* __restrict__ table,   // [3][100] from prep_dots (or null)
    const float*  __restrict__ centers, // fallback path only
    const float*  __restrict__ radii,
    const float*  __restrict__ colors,
    float* __restrict__ out)            // [3][4096][4096]
{
    __shared__ float4 s_dot[ND];        // compacted, ascending order
    __shared__ unsigned long long s_mask[2];
    __shared__ int s_cnt;

    // 1D grid decode: x fastest, plane slowest (phase-separated).
    const int bid = blockIdx.x;
    const int bx  = bid % NBX;
    const int by  = (bid / NBX) % NBY;
    const int z   = bid / (NBX * NBY);

    const int tx0 = bx * TW;
    const int ty0 = by * TH;
    const int t   = threadIdx.x;
    const int lane = t & 63;
    const int w    = t >> 6;

    const size_t plane = (size_t)z * IMG * IMG;

    // Setup: one coalesced float4 load per dot (L2-hot), cull, ballot-compact.
    int flag = 0;
    float4 d4 = make_float4(0.f, 0.f, 0.f, 0.f);
    if (t < ND) {
        if (table) {
            d4 = table[z * ND + t];
        } else {  // fallback if workspace unavailable (bit-exact same math)
            float xc = floorf(centers[2 * t]     * 4096.0f);
            float yc = floorf(centers[2 * t + 1] * 4096.0f);
            float r  = floorf(radii[t] * (4096.0f / 5.0f));
            d4 = make_float4(xc, yc, r * r, colors[3 * t + z]);
        }
        float cx = fminf(fmaxf(d4.x, (float)tx0), (float)(tx0 + TW - 1));
        float cy = fminf(fmaxf(d4.y, (float)ty0), (float)(ty0 + TH - 1));
        float dx = d4.x - cx, dy = d4.y - cy;
        flag = (dx * dx + dy * dy <= d4.z) ? 1 : 0;
    }
    if (t < 128) {
        unsigned long long m = __ballot(flag != 0);
        if (lane == 0) s_mask[w] = m;
    }
    __syncthreads();
    {
        const unsigned long long m0 = s_mask[0];
        if (flag) {
            const unsigned long long mw = s_mask[w];
            int pos = __popcll(mw & ((1ull << lane) - 1)) + (w ? __popcll(m0) : 0);
            s_dot[pos] = d4;
        }
        if (t == 0) s_cnt = __popcll(m0) + __popcll(s_mask[1]);
    }
    __syncthreads();
    const int cnt = s_cnt;

    const int x0   = tx0 + lane * 4;
    const float fx0 = (float)x0;
    const float fx1 = (float)(x0 + 1);
    const float fx2 = (float)(x0 + 2);
    const float fx3 = (float)(x0 + 3);
    const float fxL = (float)tx0;             // wave segment endpoints (uniform)
    const float fxR = (float)(tx0 + TW - 1);

    const int yb = ty0 + w * 8;               // wave owns 8 CONSECUTIVE rows
    vfloat4 ov[8];                            // statically indexed (full unroll)

    #pragma unroll
    for (int it = 0; it < 8; ++it) {
        const float fy = (float)(yb + it);

        // Descending scan: first hit == last-drawn winner (endpoint-classified).
        int b0 = -1, b1 = -1, b2 = -1, b3 = -1;
        for (int k = cnt - 1; k >= 0; --k) {
            const float4 d  = s_dot[k];        // one ds_read_b128, broadcast
            const float dy  = fy - d.y;
            const float t2  = d.z - dy * dy;   // exact integer arithmetic in fp32
            const float dl  = fxL - d.x;
            const float dr  = fxR - d.x;
            const bool  eL  = (dl * dl <= t2);
            const bool  eR  = (dr * dr <= t2);
            if (eL && eR) {                    // dot covers whole 256px segment
                if (b0 < 0) b0 = k;
                if (b1 < 0) b1 = k;
                if (b2 < 0) b2 = k;
                if (b3 < 0) b3 = k;
                break;
            }
            if (!eL && !eR && !(t2 >= 0.f && d.x >= fxL && d.x <= fxR)) continue;
            // Partial overlap: exact per-pixel tests (bit-identical to reference).
            const float dx0 = fx0 - d.x;
            const float dx1 = fx1 - d.x;
            const float dx2 = fx2 - d.x;
            const float dx3 = fx3 - d.x;
            if (b0 < 0 && dx0 * dx0 <= t2) b0 = k;
            if (b1 < 0 && dx1 * dx1 <= t2) b1 = k;
            if (b2 < 0 && dx2 * dx2 <= t2) b2 = k;
            if (b3 < 0 && dx3 * dx3 <= t2) b3 = k;
            if (__all((b0 | b1 | b2 | b3) >= 0)) break;
        }

        // Patch (this plane only) needed where no dot covers (~1.5% of pixels);
        // latency overlaps the following iterations' scans.
        float4 p = make_float4(0.f, 0.f, 0.f, 0.f);
        if ((b0 | b1 | b2 | b3) < 0) {
            const size_t base = plane + (size_t)(yb + it) * IMG + x0;
            const vfloat4 pv = __builtin_nontemporal_load((const vfloat4*)(patch + base));
            p = make_float4(pv.x, pv.y, pv.z, pv.w);
        }

        ov[it].x = (b0 >= 0) ? s_dot[b0].w : p.x;
        ov[it].y = (b1 >= 0) ? s_dot[b1].w : p.y;
        ov[it].z = (b2 >= 0) ? s_dot[b2].w : p.z;
        ov[it].w = (b3 >= 0) ? s_dot[b3].w : p.w;
    }

    // STORE BURST: 8 back-to-back nt stores, 8 consecutive rows (16KiB stride).
    const size_t base0 = plane + (size_t)yb * IMG + x0;
    #pragma unroll
    for (int it = 0; it < 8; ++it)
        __builtin_nontemporal_store(ov[it], (vfloat4*)(out + base0 + (size_t)it * IMG));
}

extern "C" void kernel_launch(void* const* d_in, const int* in_sizes, int n_in,
                              void* d_out, int out_size, void* d_ws, size_t ws_size,
                              hipStream_t stream) {
    const float* patch   = (const float*)d_in[0];
    const float* centers = (const float*)d_in[1];
    const float* radii   = (const float*)d_in[2];
    const float* colors  = (const float*)d_in[3];
    float* out = (float*)d_out;

    float4* table = nullptr;
    if (d_ws && ws_size >= 3 * ND * sizeof(float4)) {
        table = (float4*)d_ws;
        prep_dots<<<dim3(3), dim3(128), 0, stream>>>(centers, radii, colors, table);
    }

    dim3 grid(NBX * NBY * 3);  // 6144 blocks, 1D
    dim3 block(256);
    patch_dots_kernel<<<grid, block, 0, stream>>>(patch, table, centers, radii,
                                                  colors, out);
}